// Round 12
// baseline (142.090 us; speedup 1.0000x reference)
//
#include <hip/hip_runtime.h>
#include <hip/hip_fp16.h>

#define Nn 2048
#define Ff 64
#define Uu 64
#define NT 256
#define NCH 64          // chunks of 32 cols
#define G1S 68

typedef _Float16 f16x2 __attribute__((ext_vector_type(2)));
typedef _Float16 f16x8 __attribute__((ext_vector_type(8)));
typedef float    f32x4 __attribute__((ext_vector_type(4)));

#define MFMA32(a,b,c) __builtin_amdgcn_mfma_f32_16x16x32_f16(a,b,c,0,0,0)
#define GLD16(gp, lp) __builtin_amdgcn_global_load_lds(                      \
    (const __attribute__((address_space(1))) void*)(gp),                     \
    (__attribute__((address_space(3))) void*)(lp), 16, 0, 0)

// stage-buffer layout (bytes within one 20480B buffer); TRIPLE buffered
#define OD0 0
#define OD1 2048
#define OG  4096
#define OK  6144
#define OW0 8192
#define OW1 14336
#define STG 20480
#define OP   61440     // P dbuf: [c&1]{P0 1KB, P1 1KB}
#define OG1A 65536
#define OG1B 69888
#define OWS  74240     // 32 floats
#define OINV 74368     // 32 floats
#define SMSZ 74496     // ~72.8 KB -> 2 blocks/CU

// ---- X transpose: Xt[b][f][k] = (f16) X[b][k][f] (validated R4-R11) ----
__global__ __launch_bounds__(256) void transposeX(const float* __restrict__ X,
                                                  _Float16* __restrict__ Xt) {
    __shared__ _Float16 tile[64][65];
    const int b = blockIdx.x, kt = blockIdx.y;
    #pragma unroll
    for (int i = 0; i < 16; ++i) {
        int e  = i * 256 + threadIdx.x;
        int kk = e >> 6, ff = e & 63;
        tile[ff][kk] = (_Float16)X[((size_t)b * Nn + kt * 64 + kk) * Ff + ff];
    }
    __syncthreads();
    #pragma unroll
    for (int i = 0; i < 16; ++i) {
        int e  = i * 256 + threadIdx.x;
        int ff = e >> 6, kk = e & 63;
        Xt[((size_t)b * Ff + ff) * Nn + kt * 64 + kk] = tile[ff][kk];
    }
}

// One block = 16 rows x 2 batches; Geo/KL staged once, shared by both
// batches (655 MB requested vs 790). Depth-3 async staging: chunk c+2
// issued during chunk c; end-of-chunk wait is vmcnt(9) — the stage queue
// NEVER drains (T4). B-frags prefetched one chunk ahead so the compiler's
// pre-MFMA wait sits below chunk c+1 in the vmcnt queue.
__global__ __launch_bounds__(NT, 2) void fused_gcn(
    const _Float16* __restrict__ Xt,  // [B,F,N] f16
    const float* __restrict__ Dyn,    // [B,N,N]
    const float* __restrict__ Wf,     // [B,N,N,3]
    const float* __restrict__ Geo,    // [N,N]
    const float* __restrict__ KLm,    // [N,N]
    const float* __restrict__ Wd,     // [F,U]
    const float* __restrict__ bdv,    // [U]
    float* __restrict__ out)          // [B,N,U]
{
    __shared__ __align__(16) char SM[SMSZ];

    const int t    = threadIdx.x;
    const int lane = t & 63;
    const int wid  = t >> 6;
    const int r    = lane & 15;
    const int kg   = lane >> 4;
    const int gidx = blockIdx.x & 127;
    const int p    = blockIdx.x >> 7;
    const int n0   = gidx << 4;
    const int b0   = p * 2, b1 = p * 2 + 1;

    const char* dyn0 = (const char*)(Dyn + ((size_t)b0 * Nn + n0) * Nn);
    const char* dyn1 = (const char*)(Dyn + ((size_t)b1 * Nn + n0) * Nn);
    const char* geo  = (const char*)(Geo + (size_t)n0 * Nn);
    const char* klm  = (const char*)(KLm + (size_t)n0 * Nn);
    const char* wf0  = (const char*)(Wf + ((size_t)b0 * Nn + n0) * (size_t)Nn * 3);
    const char* wf1  = (const char*)(Wf + ((size_t)b1 * Nn + n0) * (size_t)Nn * 3);

    const size_t dA = (size_t)(lane >> 3) * (Nn * 4) + (size_t)(lane & 7) * 16;
    const size_t dB = dA + (size_t)8 * (Nn * 4);
#define WL(j) ((size_t)(((j)*1024 + lane*16) / 384) * (Nn*12) + (size_t)(((j)*1024 + lane*16) % 384))

    // 20 loads/chunk distributed 5 per wave
    const char *s0, *s1, *s2, *s3, *s4;
    int l0, l1, l2, l3, l4, i0, i1, i2, i3, i4;
    if (wid == 0) {
        s0 = dyn0 + dA;   l0 = OD0;        i0 = 128;
        s1 = dyn0 + dB;   l1 = OD0 + 1024; i1 = 128;
        s2 = dyn1 + dA;   l2 = OD1;        i2 = 128;
        s3 = dyn1 + dB;   l3 = OD1 + 1024; i3 = 128;
        s4 = geo  + dA;   l4 = OG;         i4 = 128;
    } else if (wid == 1) {
        s0 = geo + dB;    l0 = OG + 1024;  i0 = 128;
        s1 = klm + dA;    l1 = OK;         i1 = 128;
        s2 = klm + dB;    l2 = OK + 1024;  i2 = 128;
        s3 = wf0 + WL(0); l3 = OW0;        i3 = 384;
        s4 = wf0 + WL(1); l4 = OW0 + 1024; i4 = 384;
    } else if (wid == 2) {
        s0 = wf0 + WL(2); l0 = OW0 + 2048; i0 = 384;
        s1 = wf0 + WL(3); l1 = OW0 + 3072; i1 = 384;
        s2 = wf0 + WL(4); l2 = OW0 + 4096; i2 = 384;
        s3 = wf0 + WL(5); l3 = OW0 + 5120; i3 = 384;
        s4 = wf1 + WL(0); l4 = OW1;        i4 = 384;
    } else {
        s0 = wf1 + WL(1); l0 = OW1 + 1024; i0 = 384;
        s1 = wf1 + WL(2); l1 = OW1 + 2048; i1 = 384;
        s2 = wf1 + WL(3); l2 = OW1 + 3072; i2 = 384;
        s3 = wf1 + WL(4); l3 = OW1 + 4096; i3 = 384;
        s4 = wf1 + WL(5); l4 = OW1 + 5120; i4 = 384;
    }

#define STAGE(BUFI) { char* _b = SM + (BUFI) * STG;                   \
    GLD16(s0, _b + l0); GLD16(s1, _b + l1); GLD16(s2, _b + l2);       \
    GLD16(s3, _b + l3); GLD16(s4, _b + l4);                           \
    s0 += i0; s1 += i1; s2 += i2; s3 += i3; s4 += i4; }

    const _Float16* xw0 = Xt + (size_t)b0 * Ff * Nn
                        + (size_t)(wid * 16 + r) * Nn + (kg << 3);
    const _Float16* xw1 = Xt + (size_t)b1 * Ff * Nn
                        + (size_t)(wid * 16 + r) * Nn + (kg << 3);

    const int e = t >> 4, q = t & 15;
    f32x4 acc0 = {0.f,0.f,0.f,0.f}, acc1 = {0.f,0.f,0.f,0.f};
    float rs0 = 0.f, rs1 = 0.f;

    // ---- prologue: stage chunks 0,1; prefetch bf(0); wait chunk0 only ----
    STAGE(0);
    STAGE(1);
    f16x8 bfc0 = *(const f16x8*)xw0;      // bf for chunk 0
    f16x8 bfc1 = *(const f16x8*)xw1;
    xw0 += 32; xw1 += 32;
    // outstanding: chunk0(5), chunk1(5), bf(2) -> need chunk0: vmcnt(7)
    asm volatile("s_waitcnt vmcnt(7)" ::: "memory");
    __builtin_amdgcn_sched_barrier(0);
    __builtin_amdgcn_s_barrier();

    int pcur = 0;                          // stage buffer of chunk c
    #pragma unroll 1
    for (int c = 0; c < NCH; ++c) {
        const int pc2 = c & 1;

        // prefetch next-chunk B-frags (issued BEFORE stage of c+2)
        f16x8 bfn0, bfn1;
        if (c + 1 < NCH) {
            bfn0 = *(const f16x8*)xw0;
            bfn1 = *(const f16x8*)xw1;
            xw0 += 32; xw1 += 32;
        }
        __builtin_amdgcn_sched_barrier(0);
        if (c + 2 < NCH) { const int pst = (pcur + 2 >= 3) ? pcur - 1 : pcur + 2;
                           STAGE(pst); }
        __builtin_amdgcn_sched_barrier(0);

        // ---- exp-pass on staged chunk c (LDS in, swizzled f16 P out) ----
        {
            const char* st = SM + pcur * STG;
            const float* Dc0 = (const float*)(st + OD0);
            const float* Dc1 = (const float*)(st + OD1);
            const float* Gc  = (const float*)(st + OG);
            const float* Kc  = (const float*)(st + OK);
            const float* Wc0 = (const float*)(st + OW0);
            const float* Wc1 = (const float*)(st + OW1);
            float2 gv = *(const float2*)(Gc + e * 32 + q * 2);
            float2 kv = *(const float2*)(Kc + e * 32 + q * 2);
            float2 d0 = *(const float2*)(Dc0 + e * 32 + q * 2);
            float2 d1 = *(const float2*)(Dc1 + e * 32 + q * 2);
            float2 wa0 = *(const float2*)(Wc0 + e * 96 + q * 6);
            float2 wb0 = *(const float2*)(Wc0 + e * 96 + q * 6 + 2);
            float2 wc0 = *(const float2*)(Wc0 + e * 96 + q * 6 + 4);
            float2 wa1 = *(const float2*)(Wc1 + e * 96 + q * 6);
            float2 wb1 = *(const float2*)(Wc1 + e * 96 + q * 6 + 2);
            float2 wc1 = *(const float2*)(Wc1 + e * 96 + q * 6 + 4);
            float e00 = __expf(fminf(d0.x*wa0.x + gv.x*wa0.y + kv.x*wb0.x, 11.f));
            float e01 = __expf(fminf(d0.y*wb0.y + gv.y*wc0.x + kv.y*wc0.y, 11.f));
            float e10 = __expf(fminf(d1.x*wa1.x + gv.x*wa1.y + kv.x*wb1.x, 11.f));
            float e11 = __expf(fminf(d1.y*wb1.y + gv.y*wc1.x + kv.y*wc1.y, 11.f));
            _Float16 h00 = (_Float16)e00, h01 = (_Float16)e01;
            _Float16 h10 = (_Float16)e10, h11 = (_Float16)e11;
            rs0 += (float)h00 + (float)h01;
            rs1 += (float)h10 + (float)h11;
            char* Pbuf = SM + OP + pc2 * 2048;
            const int pa = (e * 64 + q * 4) ^ ((e & 7) << 4);
            f16x2 v0 = {h00, h01}, v1 = {h10, h11};
            *(f16x2*)(Pbuf + pa) = v0;
            *(f16x2*)(Pbuf + 1024 + pa) = v1;
        }
        asm volatile("s_waitcnt lgkmcnt(0)" ::: "memory");
        __builtin_amdgcn_sched_barrier(0);
        __builtin_amdgcn_s_barrier();

        // ---- MFMA: A from swizzled P (per batch), B from prefetched bf ----
        {
            const char* Pc = SM + OP + pc2 * 2048;
            const int ao = (r * 64 + kg * 16) ^ ((r & 7) << 4);
            f16x8 af0 = *(const f16x8*)(Pc + ao);
            f16x8 af1 = *(const f16x8*)(Pc + 1024 + ao);
            acc0 = MFMA32(af0, bfc0, acc0);
            acc1 = MFMA32(af1, bfc1, acc1);
        }
        bfc0 = bfn0; bfc1 = bfn1;          // rotate bf pipeline

        // ---- end-of-chunk: wait chunk c+1 ONLY (queue never drains) ----
        // outstanding after MFMA: chunk(c+1) 5 + bf(c+1) 4 + chunk(c+2) 5
        __builtin_amdgcn_sched_barrier(0);
        if (c + 2 < NCH) {
            asm volatile("s_waitcnt vmcnt(9)" ::: "memory");
        } else if (c + 1 < NCH) {
            asm volatile("s_waitcnt vmcnt(4)" ::: "memory");
        }
        __builtin_amdgcn_sched_barrier(0);
        __builtin_amdgcn_s_barrier();

        pcur = (pcur == 2) ? 0 : pcur + 1;
    }

    // ---- row sums (row = wid*4 + (lane>>4), 16-lane groups) ----
    float v0 = rs0, v1 = rs1;
    v0 += __shfl_xor(v0, 1, 64); v0 += __shfl_xor(v0, 2, 64);
    v0 += __shfl_xor(v0, 4, 64); v0 += __shfl_xor(v0, 8, 64);
    v1 += __shfl_xor(v1, 1, 64); v1 += __shfl_xor(v1, 2, 64);
    v1 += __shfl_xor(v1, 4, 64); v1 += __shfl_xor(v1, 8, 64);
    float* ws = (float*)(SM + OWS);
    if ((lane & 15) == 0) {
        ws[(wid << 2) + (lane >> 4)] = v0;
        ws[16 + (wid << 2) + (lane >> 4)] = v1;
    }
    __syncthreads();
    float* inv = (float*)(SM + OINV);
    if (t < 32) inv[t] = 1.0f / ws[t];
    __syncthreads();

    // ---- normalized G1 tiles (C layout validated R6/R10/R11) ----
    float* g1a = (float*)(SM + OG1A);
    float* g1b = (float*)(SM + OG1B);
    #pragma unroll
    for (int i = 0; i < 4; ++i) {
        const int ro = (kg << 2) + i;
        g1a[ro * G1S + (wid << 4) + r] = acc0[i] * inv[ro];
        g1b[ro * G1S + (wid << 4) + r] = acc1[i] * inv[16 + ro];
    }
    __syncthreads();

    // ---- Dense(64) + tanh for both batches ----
    const int row0 = wid << 2;
    const float* ga = g1a + row0 * G1S;
    const float* gb = g1b + row0 * G1S;
    float bb = bdv[lane];
    float a0 = bb, a1 = bb, a2 = bb, a3 = bb;
    float c0 = bb, c1 = bb, c2 = bb, c3 = bb;
    #pragma unroll 4
    for (int f = 0; f < Ff; ++f) {
        float wdv = Wd[f * Uu + lane];
        a0 += ga[f] * wdv;           a1 += ga[G1S + f] * wdv;
        a2 += ga[2 * G1S + f] * wdv; a3 += ga[3 * G1S + f] * wdv;
        c0 += gb[f] * wdv;           c1 += gb[G1S + f] * wdv;
        c2 += gb[2 * G1S + f] * wdv; c3 += gb[3 * G1S + f] * wdv;
    }
    float oa[4] = {a0, a1, a2, a3}, ob[4] = {c0, c1, c2, c3};
    #pragma unroll
    for (int i = 0; i < 4; ++i) {
        float x  = fminf(fmaxf(oa[i], -15.f), 15.f);
        float ex = __expf(2.f * x);
        out[((size_t)b0 * Nn + n0 + row0 + i) * Uu + lane] = (ex - 1.f) / (ex + 1.f);
        float y  = fminf(fmaxf(ob[i], -15.f), 15.f);
        float ey = __expf(2.f * y);
        out[((size_t)b1 * Nn + n0 + row0 + i) * Uu + lane] = (ey - 1.f) / (ey + 1.f);
    }
}

extern "C" void kernel_launch(void* const* d_in, const int* in_sizes, int n_in,
                              void* d_out, int out_size, void* d_ws, size_t ws_size,
                              hipStream_t stream) {
    const float* X   = (const float*)d_in[0];
    const float* Dyn = (const float*)d_in[1];
    const float* Wf  = (const float*)d_in[2];
    const float* Geo = (const float*)d_in[3];
    const float* KLm = (const float*)d_in[4];
    const float* Wd  = (const float*)d_in[5];
    const float* bdv = (const float*)d_in[6];
    float* out = (float*)d_out;

    _Float16* Xt = (_Float16*)d_ws;   // 2 MB scratch
    transposeX<<<dim3(8, Nn / 64), dim3(256), 0, stream>>>(X, Xt);
    fused_gcn<<<dim3(4 * 128), dim3(NT), 0, stream>>>(
        Xt, Dyn, Wf, Geo, KLm, Wd, bdv, out);
}

// Round 13
// 130.933 us; speedup vs baseline: 1.0852x; 1.0852x over previous
//
#include <hip/hip_runtime.h>
#include <hip/hip_fp16.h>

#define Nn 2048
#define Ff 64
#define Uu 64
#define NT 256
#define NCH 4           // chunks of 512 cols
#define G1S 68

typedef _Float16 f16x4 __attribute__((ext_vector_type(4)));
typedef _Float16 f16x8 __attribute__((ext_vector_type(8)));
typedef float    f32x4 __attribute__((ext_vector_type(4)));

#define MFMA32(a,b,c) __builtin_amdgcn_mfma_f32_16x16x32_f16(a,b,c,0,0,0)

// LDS map: P double-buffer [c&1]{P0 16KB, P1 16KB} then g1/sums
#define OPB   0
#define OG1A  65536
#define OG1B  69888
#define OWS   74240    // 32 floats
#define OINV  74368    // 32 floats
#define SMSZ  74496    // 72.8 KB -> 2 blocks/CU (grid gives 2/CU anyway)

// ---- X transpose: Xt[b][f][k] = (f16) X[b][k][f] (validated R4-R12) ----
__global__ __launch_bounds__(256) void transposeX(const float* __restrict__ X,
                                                  _Float16* __restrict__ Xt) {
    __shared__ _Float16 tile[64][65];
    const int b = blockIdx.x, kt = blockIdx.y;
    #pragma unroll
    for (int i = 0; i < 16; ++i) {
        int e  = i * 256 + threadIdx.x;
        int kk = e >> 6, ff = e & 63;
        tile[ff][kk] = (_Float16)X[((size_t)b * Nn + kt * 64 + kk) * Ff + ff];
    }
    __syncthreads();
    #pragma unroll
    for (int i = 0; i < 16; ++i) {
        int e  = i * 256 + threadIdx.x;
        int ff = e >> 6, kk = e & 63;
        Xt[((size_t)b * Ff + ff) * Nn + kt * 64 + kk] = tile[ff][kk];
    }
}

// Unit = 1 row x 256 cols, BOTH batches, Geo/KL loaded once (shared).
// Every load is 64 lanes x 16B = 1KB contiguous (R6-proven pattern).
#define ISSUE2(d0v,d1v,gv,kv,w00,w01,w02,w10,w11,w12, C, HR) {      \
    const int _rr = (HR) >> 1;                                      \
    const size_t _o = (size_t)_rr * Nn + ((size_t)(C) << 9)         \
                    + (((HR) & 1) << 8) + (lane << 2);              \
    d0v = *(const float4*)(dR0 + _o);                               \
    d1v = *(const float4*)(dR1 + _o);                               \
    gv  = *(const float4*)(gR + _o);                                \
    kv  = *(const float4*)(kR + _o);                                \
    w00 = *(const float4*)(wR0 + 3 * _o);                           \
    w01 = *(const float4*)(wR0 + 3 * _o + 4);                       \
    w02 = *(const float4*)(wR0 + 3 * _o + 8);                       \
    w10 = *(const float4*)(wR1 + 3 * _o);                           \
    w11 = *(const float4*)(wR1 + 3 * _o + 4);                       \
    w12 = *(const float4*)(wR1 + 3 * _o + 8);                       \
}

// exp for both batches -> swizzled f16 P tiles + register row-sums.
#define CONSUME2(d0v,d1v,gv,kv,w00,w01,w02,w10,w11,w12, P0B,P1B, HR) {          \
    const int _rr = (HR) >> 1;                                                  \
    const int _tr = row0 + _rr;                                                 \
    float a0 = __expf(fminf(d0v.x*w00.x + gv.x*w00.y + kv.x*w00.z, 11.f));      \
    float a1 = __expf(fminf(d0v.y*w00.w + gv.y*w01.x + kv.y*w01.y, 11.f));      \
    float a2 = __expf(fminf(d0v.z*w01.z + gv.z*w01.w + kv.z*w02.x, 11.f));      \
    float a3 = __expf(fminf(d0v.w*w02.y + gv.w*w02.z + kv.w*w02.w, 11.f));      \
    float c0 = __expf(fminf(d1v.x*w10.x + gv.x*w10.y + kv.x*w10.z, 11.f));      \
    float c1 = __expf(fminf(d1v.y*w10.w + gv.y*w11.x + kv.y*w11.y, 11.f));      \
    float c2 = __expf(fminf(d1v.z*w11.z + gv.z*w11.w + kv.z*w12.x, 11.f));      \
    float c3 = __expf(fminf(d1v.w*w12.y + gv.w*w12.z + kv.w*w12.w, 11.f));      \
    f16x4 h0 = {(_Float16)a0, (_Float16)a1, (_Float16)a2, (_Float16)a3};        \
    f16x4 h1 = {(_Float16)c0, (_Float16)c1, (_Float16)c2, (_Float16)c3};        \
    rs0[_rr] += (float)h0[0] + (float)h0[1] + (float)h0[2] + (float)h0[3];      \
    rs1[_rr] += (float)h1[0] + (float)h1[1] + (float)h1[2] + (float)h1[3];      \
    const int _ba = (_tr * 1024 + (((HR) & 1) << 9) + (lane << 3))              \
                    ^ ((_tr & 7) << 4);                                         \
    *(f16x4*)((P0B) + _ba) = h0;                                                \
    *(f16x4*)((P1B) + _ba) = h1;                                                \
}

// depth-2 A/B interleaved stage of one 512-col chunk (R6 schedule)
#define STAGE_CHUNK2(P0B, P1B, C) {                                              \
    ISSUE2(Ad0,Ad1,Agv,Akv,Aw00,Aw01,Aw02,Aw10,Aw11,Aw12, C, 0);                 \
    ISSUE2(Bd0,Bd1,Bgv,Bkv,Bw00,Bw01,Bw02,Bw10,Bw11,Bw12, C, 1);                 \
    CONSUME2(Ad0,Ad1,Agv,Akv,Aw00,Aw01,Aw02,Aw10,Aw11,Aw12, P0B,P1B, 0);         \
    ISSUE2(Ad0,Ad1,Agv,Akv,Aw00,Aw01,Aw02,Aw10,Aw11,Aw12, C, 2);                 \
    CONSUME2(Bd0,Bd1,Bgv,Bkv,Bw00,Bw01,Bw02,Bw10,Bw11,Bw12, P0B,P1B, 1);         \
    ISSUE2(Bd0,Bd1,Bgv,Bkv,Bw00,Bw01,Bw02,Bw10,Bw11,Bw12, C, 3);                 \
    CONSUME2(Ad0,Ad1,Agv,Akv,Aw00,Aw01,Aw02,Aw10,Aw11,Aw12, P0B,P1B, 2);         \
    ISSUE2(Ad0,Ad1,Agv,Akv,Aw00,Aw01,Aw02,Aw10,Aw11,Aw12, C, 4);                 \
    CONSUME2(Bd0,Bd1,Bgv,Bkv,Bw00,Bw01,Bw02,Bw10,Bw11,Bw12, P0B,P1B, 3);         \
    ISSUE2(Bd0,Bd1,Bgv,Bkv,Bw00,Bw01,Bw02,Bw10,Bw11,Bw12, C, 5);                 \
    CONSUME2(Ad0,Ad1,Agv,Akv,Aw00,Aw01,Aw02,Aw10,Aw11,Aw12, P0B,P1B, 4);         \
    ISSUE2(Ad0,Ad1,Agv,Akv,Aw00,Aw01,Aw02,Aw10,Aw11,Aw12, C, 6);                 \
    CONSUME2(Bd0,Bd1,Bgv,Bkv,Bw00,Bw01,Bw02,Bw10,Bw11,Bw12, P0B,P1B, 5);         \
    ISSUE2(Bd0,Bd1,Bgv,Bkv,Bw00,Bw01,Bw02,Bw10,Bw11,Bw12, C, 7);                 \
    CONSUME2(Ad0,Ad1,Agv,Akv,Aw00,Aw01,Aw02,Aw10,Aw11,Aw12, P0B,P1B, 6);         \
    CONSUME2(Bd0,Bd1,Bgv,Bkv,Bw00,Bw01,Bw02,Bw10,Bw11,Bw12, P0B,P1B, 7);         \
}

// MFMA over one staged 512-col chunk: B-frags prefetched in 2 groups of 8
// (live in this phase only — stage regs dead here). R8-verified form.
#define MFMA_PHASE2(PBUF, XC, ACC) {                                          \
    f16x8 p0 = *(const f16x8*)((XC));                                         \
    f16x8 p1 = *(const f16x8*)((XC) + 32);                                    \
    f16x8 p2 = *(const f16x8*)((XC) + 64);                                    \
    f16x8 p3 = *(const f16x8*)((XC) + 96);                                    \
    f16x8 p4 = *(const f16x8*)((XC) + 128);                                   \
    f16x8 p5 = *(const f16x8*)((XC) + 160);                                   \
    f16x8 p6 = *(const f16x8*)((XC) + 192);                                   \
    f16x8 p7 = *(const f16x8*)((XC) + 224);                                   \
    _Pragma("unroll")                                                         \
    for (int kk = 0; kk < 8; ++kk) {                                          \
        const int aa = r * 1024 + kk * 64 + kg * 16;                          \
        f16x8 af = *(const f16x8*)((PBUF) + (aa ^ ((r & 7) << 4)));           \
        f16x8 bv = (kk==0)?p0:(kk==1)?p1:(kk==2)?p2:(kk==3)?p3:               \
                   (kk==4)?p4:(kk==5)?p5:(kk==6)?p6:p7;                       \
        ACC = MFMA32(af, bv, ACC);                                            \
    }                                                                         \
    p0 = *(const f16x8*)((XC) + 256);                                         \
    p1 = *(const f16x8*)((XC) + 288);                                         \
    p2 = *(const f16x8*)((XC) + 320);                                         \
    p3 = *(const f16x8*)((XC) + 352);                                         \
    p4 = *(const f16x8*)((XC) + 384);                                         \
    p5 = *(const f16x8*)((XC) + 416);                                         \
    p6 = *(const f16x8*)((XC) + 448);                                         \
    p7 = *(const f16x8*)((XC) + 480);                                         \
    _Pragma("unroll")                                                         \
    for (int kk = 0; kk < 8; ++kk) {                                          \
        const int aa = r * 1024 + (kk + 8) * 64 + kg * 16;                    \
        f16x8 af = *(const f16x8*)((PBUF) + (aa ^ ((r & 7) << 4)));           \
        f16x8 bv = (kk==0)?p0:(kk==1)?p1:(kk==2)?p2:(kk==3)?p3:               \
                   (kk==4)?p4:(kk==5)?p5:(kk==6)?p6:p7;                       \
        ACC = MFMA32(af, bv, ACC);                                            \
    }                                                                         \
}

// One block = 16 rows x 2 batches (Geo/KL loaded once, shared): requested
// bytes 790 -> 677 MB chip-wide. Skeleton, chunking, load patterns and
// barrier count are R6-verbatim (the verified 6.15 TB/s rate recipe).
__global__ __launch_bounds__(NT, 2) void fused_gcn(
    const _Float16* __restrict__ Xt,  // [B,F,N] f16
    const float* __restrict__ Dyn,    // [B,N,N]
    const float* __restrict__ Wf,     // [B,N,N,3]
    const float* __restrict__ Geo,    // [N,N]
    const float* __restrict__ KLm,    // [N,N]
    const float* __restrict__ Wd,     // [F,U]
    const float* __restrict__ bdv,    // [U]
    float* __restrict__ out)          // [B,N,U]
{
    __shared__ __align__(16) char SM[SMSZ];

    const int t    = threadIdx.x;
    const int lane = t & 63;
    const int wid  = t >> 6;
    const int r    = lane & 15;
    const int kg   = lane >> 4;
    const int rg   = blockIdx.x & 127;
    const int pp   = blockIdx.x >> 7;
    const int n0   = rg << 4;
    const int b0   = pp * 2, b1 = pp * 2 + 1;
    const int row0 = wid << 2;     // this wave stages tile rows row0..row0+3

    const float* dR0 = Dyn + ((size_t)b0 * Nn + n0 + row0) * Nn;
    const float* dR1 = Dyn + ((size_t)b1 * Nn + n0 + row0) * Nn;
    const float* wR0 = Wf  + ((size_t)b0 * Nn + n0 + row0) * (size_t)Nn * 3;
    const float* wR1 = Wf  + ((size_t)b1 * Nn + n0 + row0) * (size_t)Nn * 3;
    const float* gR  = Geo + (size_t)(n0 + row0) * Nn;
    const float* kR  = KLm + (size_t)(n0 + row0) * Nn;
    const _Float16* xw0 = Xt + (size_t)b0 * Ff * Nn
                        + (size_t)(wid * 16 + r) * Nn + (kg << 3);
    const _Float16* xw1 = Xt + (size_t)b1 * Ff * Nn
                        + (size_t)(wid * 16 + r) * Nn + (kg << 3);

    f32x4 acc0 = {0.f,0.f,0.f,0.f}, acc1 = {0.f,0.f,0.f,0.f};
    float rs0[4] = {0.f,0.f,0.f,0.f}, rs1[4] = {0.f,0.f,0.f,0.f};
    float4 Ad0,Ad1,Agv,Akv,Aw00,Aw01,Aw02,Aw10,Aw11,Aw12;
    float4 Bd0,Bd1,Bgv,Bkv,Bw00,Bw01,Bw02,Bw10,Bw11,Bw12;

    // prologue: stage chunk 0
    STAGE_CHUNK2(SM + OPB, SM + OPB + 16384, 0);
    __syncthreads();

    #pragma unroll 1
    for (int c = 0; c < NCH; ++c) {
        char* bufc = SM + OPB + (c & 1) * 32768;
        MFMA_PHASE2(bufc,          xw0 + ((size_t)c << 9), acc0);
        MFMA_PHASE2(bufc + 16384,  xw1 + ((size_t)c << 9), acc1);
        if (c + 1 < NCH) {
            char* bufn = SM + OPB + ((c + 1) & 1) * 32768;
            STAGE_CHUNK2(bufn, bufn + 16384, c + 1);
        }
        __syncthreads();
    }

    // ---- row sums -> inv (batch0 rows 0-15, batch1 rows 16-31) ----
    float* ws = (float*)(SM + OWS);
    #pragma unroll
    for (int i = 0; i < 4; ++i) {
        float v = rs0[i];
        v += __shfl_xor(v, 1, 64);  v += __shfl_xor(v, 2, 64);
        v += __shfl_xor(v, 4, 64);  v += __shfl_xor(v, 8, 64);
        v += __shfl_xor(v, 16, 64); v += __shfl_xor(v, 32, 64);
        float u = rs1[i];
        u += __shfl_xor(u, 1, 64);  u += __shfl_xor(u, 2, 64);
        u += __shfl_xor(u, 4, 64);  u += __shfl_xor(u, 8, 64);
        u += __shfl_xor(u, 16, 64); u += __shfl_xor(u, 32, 64);
        if (lane == 0) { ws[row0 + i] = v; ws[16 + row0 + i] = u; }
    }
    __syncthreads();
    float* inv = (float*)(SM + OINV);
    if (t < 32) inv[t] = 1.0f / ws[t];
    __syncthreads();

    // ---- normalized G1 tiles (C layout validated R6/R10/R11) ----
    float* g1a = (float*)(SM + OG1A);
    float* g1b = (float*)(SM + OG1B);
    #pragma unroll
    for (int i = 0; i < 4; ++i) {
        const int ro = (kg << 2) + i;
        g1a[ro * G1S + (wid << 4) + r] = acc0[i] * inv[ro];
        g1b[ro * G1S + (wid << 4) + r] = acc1[i] * inv[16 + ro];
    }
    __syncthreads();

    // ---- Dense(64) + tanh for both batches (R11-verified epilogue) ----
    const float* ga = g1a + row0 * G1S;
    const float* gb = g1b + row0 * G1S;
    float bb = bdv[lane];
    float a0 = bb, a1 = bb, a2 = bb, a3 = bb;
    float c0 = bb, c1 = bb, c2 = bb, c3 = bb;
    #pragma unroll 4
    for (int f = 0; f < Ff; ++f) {
        float wdv = Wd[f * Uu + lane];
        a0 += ga[f] * wdv;           a1 += ga[G1S + f] * wdv;
        a2 += ga[2 * G1S + f] * wdv; a3 += ga[3 * G1S + f] * wdv;
        c0 += gb[f] * wdv;           c1 += gb[G1S + f] * wdv;
        c2 += gb[2 * G1S + f] * wdv; c3 += gb[3 * G1S + f] * wdv;
    }
    float oa[4] = {a0, a1, a2, a3}, ob[4] = {c0, c1, c2, c3};
    #pragma unroll
    for (int i = 0; i < 4; ++i) {
        float x  = fminf(fmaxf(oa[i], -15.f), 15.f);
        float ex = __expf(2.f * x);
        out[((size_t)b0 * Nn + n0 + row0 + i) * Uu + lane] = (ex - 1.f) / (ex + 1.f);
        float y  = fminf(fmaxf(ob[i], -15.f), 15.f);
        float ey = __expf(2.f * y);
        out[((size_t)b1 * Nn + n0 + row0 + i) * Uu + lane] = (ey - 1.f) / (ey + 1.f);
    }
}

extern "C" void kernel_launch(void* const* d_in, const int* in_sizes, int n_in,
                              void* d_out, int out_size, void* d_ws, size_t ws_size,
                              hipStream_t stream) {
    const float* X   = (const float*)d_in[0];
    const float* Dyn = (const float*)d_in[1];
    const float* Wf  = (const float*)d_in[2];
    const float* Geo = (const float*)d_in[3];
    const float* KLm = (const float*)d_in[4];
    const float* Wd  = (const float*)d_in[5];
    const float* bdv = (const float*)d_in[6];
    float* out = (float*)d_out;

    _Float16* Xt = (_Float16*)d_ws;   // 2 MB scratch
    transposeX<<<dim3(8, Nn / 64), dim3(256), 0, stream>>>(X, Xt);
    fused_gcn<<<dim3(4 * 128), dim3(NT), 0, stream>>>(
        Xt, Dyn, Wf, Geo, KLm, Wd, bdv, out);
}